// Round 7
// baseline (1835.693 us; speedup 1.0000x reference)
//
#include <hip/hip_runtime.h>
#include <stdint.h>

// ---------------------------------------------------------------------------
// SpatialAggregator: axial attention, B=8 C=512 H=W=64, DEPTH=4, HEADS=8
// R7: qkv_attn = one wave per (seq,head), no Y-LDS (global reads, L1/L2/L3
// reuse), 2KB scratch/wave, no barriers, 16 waves/CU.  Out-proj = gemm256.
// All buffers canonical (b,h,w) order; axis handled via row stride.
// ---------------------------------------------------------------------------

typedef __attribute__((ext_vector_type(8))) short bf16x8;
typedef __attribute__((ext_vector_type(4))) float f32x4;
typedef unsigned short u16;
typedef unsigned int u32;

#define MFMA16(a, b, c) __builtin_amdgcn_mfma_f32_16x16x32_bf16((a), (b), (c), 0, 0, 0)
#define SBAR() __builtin_amdgcn_sched_barrier(0)

__device__ __forceinline__ float b2f(u16 h) {
    u32 u = ((u32)h) << 16;
    float f;
    __builtin_memcpy(&f, &u, 4);
    return f;
}
__device__ __forceinline__ u16 f2b(float f) {
    u32 u;
    __builtin_memcpy(&u, &f, 4);
    u32 r = (u + 0x7fffu + ((u >> 16) & 1u)) >> 16;   // RNE
    return (u16)r;
}
__device__ __forceinline__ uint2 pack4(const f32x4& v) {
    uint2 pk;
    pk.x = (u32)f2b(v[0]) | ((u32)f2b(v[1]) << 16);
    pk.y = (u32)f2b(v[2]) | ((u32)f2b(v[3]) << 16);
    return pk;
}

#define GLD_LDS16(g, l)                                                        \
    __builtin_amdgcn_global_load_lds(                                          \
        (const __attribute__((address_space(1))) void*)(g),                    \
        (__attribute__((address_space(3))) void*)(l), 16, 0, 0)

// ---------------------------------------------------------------------------
// embed: x (B,C,H,W) f32 + pos_h (C,H) + pos_w (C,W) -> y (B,H,W,C) bf16
// ---------------------------------------------------------------------------
__global__ __launch_bounds__(256) void embed_kernel(
    const float* __restrict__ x, const float* __restrict__ ph,
    const float* __restrict__ pw, u16* __restrict__ y)
{
    __shared__ float tile[64][65];
    const int c0 = blockIdx.x * 64, h = blockIdx.y, b = blockIdx.z;
    const int t = threadIdx.x;
#pragma unroll
    for (int i = 0; i < 4; ++i) {
        int cl = (t >> 4) + i * 16;
        int w4 = (t & 15) * 4;
        const float* src = x + (((size_t)(b * 512 + c0 + cl)) * 64 + h) * 64 + w4;
        float4 v = *(const float4*)src;
        float p = ph[(c0 + cl) * 64 + h];
        tile[cl][w4 + 0] = v.x + p + pw[(c0 + cl) * 64 + w4 + 0];
        tile[cl][w4 + 1] = v.y + p + pw[(c0 + cl) * 64 + w4 + 1];
        tile[cl][w4 + 2] = v.z + p + pw[(c0 + cl) * 64 + w4 + 2];
        tile[cl][w4 + 3] = v.w + p + pw[(c0 + cl) * 64 + w4 + 3];
    }
    __syncthreads();
    const int wl = t >> 2, cb = (t & 3) * 16;
    bf16x8 o0, o1;
#pragma unroll
    for (int j = 0; j < 8; ++j) o0[j] = (short)f2b(tile[cb + j][wl]);
#pragma unroll
    for (int j = 0; j < 8; ++j) o1[j] = (short)f2b(tile[cb + 8 + j][wl]);
    u16* dst = y + (((size_t)(b * 64 + h) * 64 + wl) * 512 + c0 + cb);
    *(bf16x8*)dst = o0;
    *(bf16x8*)(dst + 8) = o1;
}

// ---------------------------------------------------------------------------
// weight transpose: W[k][n] f32 -> WT[n][k] bf16, all 24 matrices.
// wT per (l,axis): [ qT 512x512 | kvT 1024x512 | woT 512x512 ], ld=512
// ---------------------------------------------------------------------------
__global__ __launch_bounds__(256) void wtrans_kernel(
    const float* __restrict__ wq, const float* __restrict__ wkv,
    const float* __restrict__ wo, u16* __restrict__ wT)
{
    const int mid = blockIdx.z;
    const int l = mid / 6, rest = mid % 6, axis = rest / 3, which = rest % 3;
    const size_t la = (size_t)(l * 2 + axis);
    const float* src;
    int N;
    size_t doff;
    if (which == 0)      { src = wq  + la * 512 * 512;  N = 512;  doff = la * (2048 * 512); }
    else if (which == 1) { src = wkv + la * 512 * 1024; N = 1024; doff = la * (2048 * 512) + 512 * 512; }
    else                 { src = wo  + la * 512 * 512;  N = 512;  doff = la * (2048 * 512) + 512 * 512 + 1024 * 512; }
    const int n0 = blockIdx.y * 64;
    if (n0 >= N) return;
    const int k0 = blockIdx.x * 64;
    __shared__ float tile[64][65];
    const int t = threadIdx.x;
#pragma unroll
    for (int i = 0; i < 4; ++i) {
        int kl = (t >> 4) + i * 16;
        int n4 = (t & 15) * 4;
        float4 v = *(const float4*)(src + (size_t)(k0 + kl) * N + n0 + n4);
        tile[kl][n4 + 0] = v.x; tile[kl][n4 + 1] = v.y;
        tile[kl][n4 + 2] = v.z; tile[kl][n4 + 3] = v.w;
    }
    __syncthreads();
    const int nl = t >> 2, kb = (t & 3) * 16;
    bf16x8 o0, o1;
#pragma unroll
    for (int j = 0; j < 8; ++j) o0[j] = (short)f2b(tile[kb + j][nl]);
#pragma unroll
    for (int j = 0; j < 8; ++j) o1[j] = (short)f2b(tile[kb + 8 + j][nl]);
    u16* dst = wT + doff + (size_t)(n0 + nl) * 512 + k0 + kb;
    *(bf16x8*)dst = o0;
    *(bf16x8*)(dst + 8) = o1;
}

// ---------------------------------------------------------------------------
// qkv_attn: one WAVE per (seq, head); 4 waves/block = 4 heads of one seq
// (shared y reads -> L1 reuse).  Y read directly from global (canonical
// (b,h,w) rows; axis picks row stride).  K/Q/V projections accumulate in one
// shared acc[4][4]; transposes via 2KB/wave LDS scratch (4x 16-row passes).
// Attention (S^T, softmax, PV) as verified in R3/R6.  O -> global, canonical
// token rows, head column slice.  No barriers anywhere.
// ---------------------------------------------------------------------------
template <int AXIS>
__global__ __launch_bounds__(256, 4) void qkv_attn(
    const u16* __restrict__ y,
    const u16* __restrict__ wTla,
    u16* __restrict__ O)
{
    __shared__ u16 scrb[4][1024];           // 2KB scratch per wave
    const int tid = threadIdx.x, lane = tid & 63, wv = tid >> 6;
    const int unit = blockIdx.x * 4 + wv;   // 4096 = 512 seq x 8 heads
    const int seq = unit >> 3, head = unit & 7;
    const int l16 = lane & 15, g = lane >> 4;
    const size_t rowbase = ((size_t)(seq >> 6) << 12) +
                           (AXIS == 0 ? (size_t)(seq & 63) : ((size_t)(seq & 63) << 6));
    const int rowstr = (AXIS == 0) ? 64 : 1;
    u16* scr = (u16*)scrb[wv];

    const int hoff = head * 64;
    const u16* wq_ = wTla + (size_t)hoff * 512;
    const u16* wk_ = wTla + (size_t)(512 + hoff) * 512;
    const u16* wv_ = wTla + (size_t)(1024 + hoff) * 512;

    // y fragment straight from global: row r (token), K-step t, chunk g
#define YG(r, t) (*(const bf16x8*)(y + (rowbase + (size_t)(r) * rowstr) * 512 + (t) * 32 + g * 8))
    // per-pass scratch (16 rows x 128B): row = l16
#define SW16(bo, val) *(uint2*)((char*)scr + l16 * 128 + ((bo) ^ ((l16 & 7) << 4))) = (val)
#define SF16(k2) (*(const bf16x8*)((const char*)scr + l16 * 128 + \
                    (((k2) * 64 + g * 16) ^ ((l16 & 7) << 4))))

    f32x4 acc[4][4];
    bf16x8 kf[4][2], qf[4][2];

    // ---- K projection: acc[ef][jf] = D[e][j] ----
#pragma unroll
    for (int ef = 0; ef < 4; ++ef)
#pragma unroll
        for (int jf = 0; jf < 4; ++jf) acc[ef][jf] = f32x4{0.f, 0.f, 0.f, 0.f};
#pragma unroll
    for (int t = 0; t < 16; ++t) {
        bf16x8 yf[4], wf[4];
#pragma unroll
        for (int f = 0; f < 4; ++f) {
            int row = f * 16 + l16;
            yf[f] = YG(row, t);
            wf[f] = *(const bf16x8*)(wk_ + (size_t)row * 512 + t * 32 + g * 8);
        }
#pragma unroll
        for (int ef = 0; ef < 4; ++ef)
#pragma unroll
            for (int jf = 0; jf < 4; ++jf)
                acc[ef][jf] = MFMA16(wf[ef], yf[jf], acc[ef][jf]);
    }
    // 4-pass transpose: K operand rows j, k-contig e
#pragma unroll
    for (int jf = 0; jf < 4; ++jf) {
#pragma unroll
        for (int ef = 0; ef < 4; ++ef)
            SW16((ef * 16 + g * 4) * 2, pack4(acc[ef][jf]));
        SBAR();
        kf[jf][0] = SF16(0);
        kf[jf][1] = SF16(1);
        SBAR();
    }

    // ---- Q projection (same structure) ----
#pragma unroll
    for (int ef = 0; ef < 4; ++ef)
#pragma unroll
        for (int jf = 0; jf < 4; ++jf) acc[ef][jf] = f32x4{0.f, 0.f, 0.f, 0.f};
#pragma unroll
    for (int t = 0; t < 16; ++t) {
        bf16x8 yf[4], wf[4];
#pragma unroll
        for (int f = 0; f < 4; ++f) {
            int row = f * 16 + l16;
            yf[f] = YG(row, t);
            wf[f] = *(const bf16x8*)(wq_ + (size_t)row * 512 + t * 32 + g * 8);
        }
#pragma unroll
        for (int ef = 0; ef < 4; ++ef)
#pragma unroll
            for (int jf = 0; jf < 4; ++jf)
                acc[ef][jf] = MFMA16(wf[ef], yf[jf], acc[ef][jf]);
    }
#pragma unroll
    for (int jf = 0; jf < 4; ++jf) {
#pragma unroll
        for (int ef = 0; ef < 4; ++ef)
            SW16((ef * 16 + g * 4) * 2, pack4(acc[ef][jf]));
        SBAR();
        qf[jf][0] = SF16(0);
        qf[jf][1] = SF16(1);
        SBAR();
    }

    // ---- S^T = mfma(K, Q): rows j = jf*16+g*4+r, cols i = if*16+l16 ----
    f32x4 st[4][4] = {};
#pragma unroll
    for (int k2 = 0; k2 < 2; ++k2)
#pragma unroll
        for (int i_f = 0; i_f < 4; ++i_f)
#pragma unroll
            for (int j_f = 0; j_f < 4; ++j_f)
                st[i_f][j_f] = MFMA16(kf[j_f][k2], qf[i_f][k2], st[i_f][j_f]);

    // ---- softmax over j per i; P -> pf via per-i_f scratch pass ----
    bf16x8 pf[4][2];
#pragma unroll
    for (int i_f = 0; i_f < 4; ++i_f) {
        float ev[4][4];
        float mx = -1e30f;
#pragma unroll
        for (int j_f = 0; j_f < 4; ++j_f)
#pragma unroll
            for (int r = 0; r < 4; ++r) {
                float v = st[i_f][j_f][r] * 0.125f;
                ev[j_f][r] = v;
                mx = fmaxf(mx, v);
            }
        mx = fmaxf(mx, __shfl_xor(mx, 16, 64));
        mx = fmaxf(mx, __shfl_xor(mx, 32, 64));
        float sum = 0.f;
#pragma unroll
        for (int j_f = 0; j_f < 4; ++j_f)
#pragma unroll
            for (int r = 0; r < 4; ++r) {
                float e = __expf(ev[j_f][r] - mx);
                ev[j_f][r] = e;
                sum += e;
            }
        sum += __shfl_xor(sum, 16, 64);
        sum += __shfl_xor(sum, 32, 64);
        float inv = __builtin_amdgcn_rcpf(sum);
#pragma unroll
        for (int j_f = 0; j_f < 4; ++j_f) {
            uint2 pk;
            pk.x = (u32)f2b(ev[j_f][0] * inv) | ((u32)f2b(ev[j_f][1] * inv) << 16);
            pk.y = (u32)f2b(ev[j_f][2] * inv) | ((u32)f2b(ev[j_f][3] * inv) << 16);
            SW16(j_f * 32 + g * 8, pk);
        }
        SBAR();
        pf[i_f][0] = SF16(0);
        pf[i_f][1] = SF16(1);
        SBAR();
    }

    // ---- V projection: acc[jf][ef] = D[j][e] ----
#pragma unroll
    for (int jf = 0; jf < 4; ++jf)
#pragma unroll
        for (int ef = 0; ef < 4; ++ef) acc[jf][ef] = f32x4{0.f, 0.f, 0.f, 0.f};
#pragma unroll
    for (int t = 0; t < 16; ++t) {
        bf16x8 yf[4], wf[4];
#pragma unroll
        for (int f = 0; f < 4; ++f) {
            int row = f * 16 + l16;
            yf[f] = YG(row, t);
            wf[f] = *(const bf16x8*)(wv_ + (size_t)row * 512 + t * 32 + g * 8);
        }
#pragma unroll
        for (int jf = 0; jf < 4; ++jf)
#pragma unroll
            for (int ef = 0; ef < 4; ++ef)
                acc[jf][ef] = MFMA16(yf[jf], wf[ef], acc[jf][ef]);
    }
    // 4-pass transpose: V^T operand rows e, k-contig j
    bf16x8 vtf[4][2];
#pragma unroll
    for (int ef = 0; ef < 4; ++ef) {
#pragma unroll
        for (int jf = 0; jf < 4; ++jf)
            SW16((jf * 16 + g * 4) * 2, pack4(acc[jf][ef]));
        SBAR();
        vtf[ef][0] = SF16(0);
        vtf[ef][1] = SF16(1);
        SBAR();
    }

    // ---- O^T = mfma(V^T, P): rows e = ef*16+g*4+r, cols i = if*16+l16 ----
    f32x4 of[4][4] = {};   // [ef][if]
#pragma unroll
    for (int k2 = 0; k2 < 2; ++k2)
#pragma unroll
        for (int ef = 0; ef < 4; ++ef)
#pragma unroll
            for (int i_f = 0; i_f < 4; ++i_f)
                of[ef][i_f] = MFMA16(vtf[ef][k2], pf[i_f][k2], of[ef][i_f]);

    // ---- store O: token row i (canonical), head column slice; 8B stores ----
#pragma unroll
    for (int i_f = 0; i_f < 4; ++i_f) {
        const int i = i_f * 16 + l16;
        u16* orow = O + (rowbase + (size_t)i * rowstr) * 512 + hoff + g * 4;
#pragma unroll
        for (int ef = 0; ef < 4; ++ef)
            *(uint2*)(orow + ef * 16) = pack4(of[ef][i_f]);
    }
#undef YG
#undef SW16
#undef SF16
}

// ---------------------------------------------------------------------------
// GEMM 256x256 tile, BK=64, 8 waves (2M x 4N), counted-vmcnt double-buffered
// (verified R4).  C = A[M,512] @ WT[N,512]^T + bias (+in-place add).
// MODE: 1=+bias, 2=+bias+inplace add.
// ---------------------------------------------------------------------------
template <int MODE>
__global__ __launch_bounds__(512, 2) void gemm256(
    const u16* __restrict__ A, int lda,
    const u16* __restrict__ Bt,
    const float* __restrict__ bias,
    u16* C, int ldc)
{
    __shared__ u16 As[2][256 * 64];
    __shared__ u16 Bs[2][256 * 64];
    const int tid = threadIdx.x, lane = tid & 63, wid = tid >> 6;
    const int wm = wid >> 2, wn = wid & 3;
    int lin = blockIdx.x + gridDim.x * blockIdx.y;  // n-fast
    int cpx = (gridDim.x * gridDim.y) >> 3;         // nwg % 8 == 0
    int id = (lin & 7) * cpx + (lin >> 3);          // bijective XCD chunks
    const int n0 = (id % gridDim.x) * 256;
    const int m0 = (id / gridDim.x) * 256;
    const int rl = lane >> 3, cp = lane & 7, l16 = lane & 15, g = lane >> 4;

    f32x4 acc[4][8] = {};                           // [nf][mf], D rows = n

#define STAGE(b, ks)                                                           \
    {                                                                          \
        _Pragma("unroll")                                                      \
        for (int j = 0; j < 4; ++j) {                                          \
            int grp = wid + 8 * j;                                             \
            int row = grp * 8 + rl;                                            \
            const u16* s = A + (size_t)(m0 + row) * lda + (ks) + (cp ^ (row & 7)) * 8; \
            GLD_LDS16(s, As[b] + grp * 512);                                   \
        }                                                                      \
        _Pragma("unroll")                                                      \
        for (int j = 0; j < 4; ++j) {                                          \
            int grp = wid + 8 * j;                                             \
            int row = grp * 8 + rl;                                            \
            const u16* s = Bt + (size_t)(n0 + row) * 512 + (ks) + (cp ^ (row & 7)) * 8; \
            GLD_LDS16(s, Bs[b] + grp * 512);                                   \
        }                                                                      \
    }

#define FRAG(base, row, kk)                                                    \
    (*(const bf16x8*)((const char*)(base) + (row) * 128 +                      \
                      (((kk) * 64 + g * 16) ^ (((row) & 7) << 4))))

    STAGE(0, 0);

    for (int t = 0; t < 8; ++t) {
        const int cb = t & 1;
        if (t < 7) STAGE(cb ^ 1, (t + 1) * 64);
        __builtin_amdgcn_sched_barrier(0);
        if (t < 7) { asm volatile("s_waitcnt vmcnt(8)" ::: "memory"); }
        else       { asm volatile("s_waitcnt vmcnt(0)" ::: "memory"); }
        __builtin_amdgcn_s_barrier();
        __builtin_amdgcn_sched_barrier(0);

        const u16* cA = As[cb];
        const u16* cB = Bs[cb];
        bf16x8 bl[2][2], bh[2][2], af[4][2];

#pragma unroll
        for (int nf = 0; nf < 2; ++nf)
#pragma unroll
            for (int kk = 0; kk < 2; ++kk)
                bl[nf][kk] = FRAG(cB, wn * 64 + nf * 16 + l16, kk);
#pragma unroll
        for (int mf = 0; mf < 4; ++mf)
#pragma unroll
            for (int kk = 0; kk < 2; ++kk)
                af[mf][kk] = FRAG(cA, wm * 128 + mf * 16 + l16, kk);
        __builtin_amdgcn_s_setprio(1);
#pragma unroll
        for (int kk = 0; kk < 2; ++kk)
#pragma unroll
            for (int nf = 0; nf < 2; ++nf)
#pragma unroll
                for (int mf = 0; mf < 4; ++mf)
                    acc[nf][mf] = MFMA16(bl[nf][kk], af[mf][kk], acc[nf][mf]);
        __builtin_amdgcn_s_setprio(0);

#pragma unroll
        for (int nf = 0; nf < 2; ++nf)
#pragma unroll
            for (int kk = 0; kk < 2; ++kk)
                bh[nf][kk] = FRAG(cB, wn * 64 + 32 + nf * 16 + l16, kk);
        __builtin_amdgcn_s_setprio(1);
#pragma unroll
        for (int kk = 0; kk < 2; ++kk)
#pragma unroll
            for (int nf = 0; nf < 2; ++nf)
#pragma unroll
                for (int mf = 0; mf < 4; ++mf)
                    acc[2 + nf][mf] = MFMA16(bh[nf][kk], af[mf][kk], acc[2 + nf][mf]);
        __builtin_amdgcn_s_setprio(0);

#pragma unroll
        for (int mf = 0; mf < 4; ++mf)
#pragma unroll
            for (int kk = 0; kk < 2; ++kk)
                af[mf][kk] = FRAG(cA, wm * 128 + 64 + mf * 16 + l16, kk);
        __builtin_amdgcn_s_setprio(1);
#pragma unroll
        for (int kk = 0; kk < 2; ++kk)
#pragma unroll
            for (int nf = 0; nf < 2; ++nf)
#pragma unroll
                for (int mf = 0; mf < 4; ++mf)
                    acc[2 + nf][4 + mf] = MFMA16(bh[nf][kk], af[mf][kk], acc[2 + nf][4 + mf]);
        __builtin_amdgcn_s_setprio(0);

        __builtin_amdgcn_s_setprio(1);
#pragma unroll
        for (int kk = 0; kk < 2; ++kk)
#pragma unroll
            for (int nf = 0; nf < 2; ++nf)
#pragma unroll
                for (int mf = 0; mf < 4; ++mf)
                    acc[nf][4 + mf] = MFMA16(bl[nf][kk], af[mf][kk], acc[nf][4 + mf]);
        __builtin_amdgcn_s_setprio(0);

        __builtin_amdgcn_sched_barrier(0);
        __builtin_amdgcn_s_barrier();
        __builtin_amdgcn_sched_barrier(0);
    }

    float bv[4][4];
#pragma unroll
    for (int nf = 0; nf < 4; ++nf) {
        float4 b4 = *(const float4*)(bias + n0 + wn * 64 + nf * 16 + g * 4);
        bv[nf][0] = b4.x; bv[nf][1] = b4.y; bv[nf][2] = b4.z; bv[nf][3] = b4.w;
    }
#pragma unroll
    for (int mf = 0; mf < 8; ++mf) {
        const int m = m0 + wm * 128 + mf * 16 + l16;
        u16* crow = C + (size_t)m * ldc;
#pragma unroll
        for (int nf = 0; nf < 4; ++nf) {
            const int n = n0 + wn * 64 + nf * 16 + g * 4;
            u16* cptr = crow + n;
            float v0 = acc[nf][mf][0], v1 = acc[nf][mf][1];
            float v2 = acc[nf][mf][2], v3 = acc[nf][mf][3];
            v0 += bv[nf][0]; v1 += bv[nf][1]; v2 += bv[nf][2]; v3 += bv[nf][3];
            if (MODE == 2) {
                ushort4 o = *(const ushort4*)cptr;
                v0 += b2f(o.x); v1 += b2f(o.y); v2 += b2f(o.z); v3 += b2f(o.w);
            }
            uint2 pk;
            pk.x = (u32)f2b(v0) | ((u32)f2b(v1) << 16);
            pk.y = (u32)f2b(v2) | ((u32)f2b(v3) << 16);
            *(uint2*)cptr = pk;
        }
    }
#undef STAGE
#undef FRAG
}

// ---------------------------------------------------------------------------
// final: y (B,H,W,C) bf16 -> out (B,C,H,W) f32
// ---------------------------------------------------------------------------
__global__ __launch_bounds__(256) void untrans_kernel(
    const u16* __restrict__ y, float* __restrict__ out)
{
    __shared__ float tile[64][65];   // [w][c]
    const int c0 = blockIdx.x * 64, h = blockIdx.y, b = blockIdx.z;
    const int t = threadIdx.x;
    {
        const int wl = t >> 2, cb = (t & 3) * 16;
        const u16* src = y + (((size_t)(b * 64 + h) * 64 + wl) * 512 + c0 + cb);
        bf16x8 v0 = *(const bf16x8*)src;
        bf16x8 v1 = *(const bf16x8*)(src + 8);
#pragma unroll
        for (int j = 0; j < 8; ++j) tile[wl][cb + j] = b2f((u16)v0[j]);
#pragma unroll
        for (int j = 0; j < 8; ++j) tile[wl][cb + 8 + j] = b2f((u16)v1[j]);
    }
    __syncthreads();
    const int cl = t >> 2, w16 = (t & 3) * 16;
    float* dst = out + (((size_t)(b * 512 + c0 + cl)) * 64 + h) * 64 + w16;
#pragma unroll
    for (int j = 0; j < 4; ++j) {
        float4 v;
        v.x = tile[w16 + j * 4 + 0][cl];
        v.y = tile[w16 + j * 4 + 1][cl];
        v.z = tile[w16 + j * 4 + 2][cl];
        v.w = tile[w16 + j * 4 + 3][cl];
        *(float4*)(dst + j * 4) = v;
    }
}

// ---------------------------------------------------------------------------
extern "C" void kernel_launch(void* const* d_in, const int* in_sizes, int n_in,
                              void* d_out, int out_size, void* d_ws, size_t ws_size,
                              hipStream_t stream)
{
    (void)in_sizes; (void)n_in; (void)out_size; (void)ws_size;
    const float* x   = (const float*)d_in[0];
    const float* ph  = (const float*)d_in[1];
    const float* pw  = (const float*)d_in[2];
    const float* wq  = (const float*)d_in[3];
    const float* wkv = (const float*)d_in[4];
    const float* wo  = (const float*)d_in[5];
    const float* wob = (const float*)d_in[6];

    char* ws = (char*)d_ws;
    u16* yA = (u16*)(ws);                   // 32 MB
    u16* yB = (u16*)(ws + 33554432);        // 32 MB
    u16* O  = (u16*)(ws + 67108864);        // 32 MB: attention output
    u16* wT = (u16*)(ws + 100663296);       // 16 MB: transposed weights bf16
    float* out = (float*)d_out;

    embed_kernel<<<dim3(8, 64, 8), 256, 0, stream>>>(x, ph, pw, yA);
    wtrans_kernel<<<dim3(8, 16, 24), 256, 0, stream>>>(wq, wkv, wo, wT);

    u16* yin = yA;
    u16* yout = yB;
    for (int l = 0; l < 4; ++l) {
        for (int axis = 0; axis < 2; ++axis) {
            const u16* wTla = wT + (size_t)(l * 2 + axis) * 2048 * 512;
            const float* bias = wob + (size_t)(l * 2 + axis) * 512;
            const u16* woT = wTla + 512 * 512 + 1024 * 512;
            if (axis == 0) {
                qkv_attn<0><<<dim3(1024), 256, 0, stream>>>(yin, wTla, O);
                gemm256<1><<<dim3(2, 128), 512, 0, stream>>>(O, 512, woT, bias, yout, 512);
            } else {
                qkv_attn<1><<<dim3(1024), 256, 0, stream>>>(yin, wTla, O);
                gemm256<2><<<dim3(2, 128), 512, 0, stream>>>(O, 512, woT, bias, yout, 512);
            }
        }
        u16* tmp = yin; yin = yout; yout = tmp;
    }
    untrans_kernel<<<dim3(8, 64, 8), 256, 0, stream>>>(yin, out);
}

// Round 8
// 1357.151 us; speedup vs baseline: 1.3526x; 1.3526x over previous
//
#include <hip/hip_runtime.h>
#include <stdint.h>

// ---------------------------------------------------------------------------
// SpatialAggregator: axial attention, B=8 C=512 H=W=64, DEPTH=4, HEADS=8
// R8: R6 fused kernel + occupancy unblock: 1KB/wave scratch (two k-half
// sub-passes per transpose), LDS 72KB -> 2 blocks/CU, VGPR capped 128.
// ---------------------------------------------------------------------------

typedef __attribute__((ext_vector_type(8))) short bf16x8;
typedef __attribute__((ext_vector_type(4))) float f32x4;
typedef unsigned short u16;
typedef unsigned int u32;

#define MFMA16(a, b, c) __builtin_amdgcn_mfma_f32_16x16x32_bf16((a), (b), (c), 0, 0, 0)
#define SBAR() __builtin_amdgcn_sched_barrier(0)

__device__ __forceinline__ float b2f(u16 h) {
    u32 u = ((u32)h) << 16;
    float f;
    __builtin_memcpy(&f, &u, 4);
    return f;
}
__device__ __forceinline__ u16 f2b(float f) {
    u32 u;
    __builtin_memcpy(&u, &f, 4);
    u32 r = (u + 0x7fffu + ((u >> 16) & 1u)) >> 16;   // RNE
    return (u16)r;
}
__device__ __forceinline__ uint2 pack4(const f32x4& v) {
    uint2 pk;
    pk.x = (u32)f2b(v[0]) | ((u32)f2b(v[1]) << 16);
    pk.y = (u32)f2b(v[2]) | ((u32)f2b(v[3]) << 16);
    return pk;
}

#define GLD_LDS16(g, l)                                                        \
    __builtin_amdgcn_global_load_lds(                                          \
        (const __attribute__((address_space(1))) void*)(g),                    \
        (__attribute__((address_space(3))) void*)(l), 16, 0, 0)

// ---------------------------------------------------------------------------
// embed: x (B,C,H,W) f32 + pos_h (C,H) + pos_w (C,W) -> y (B,H,W,C) bf16
// ---------------------------------------------------------------------------
__global__ __launch_bounds__(256) void embed_kernel(
    const float* __restrict__ x, const float* __restrict__ ph,
    const float* __restrict__ pw, u16* __restrict__ y)
{
    __shared__ float tile[64][65];
    const int c0 = blockIdx.x * 64, h = blockIdx.y, b = blockIdx.z;
    const int t = threadIdx.x;
#pragma unroll
    for (int i = 0; i < 4; ++i) {
        int cl = (t >> 4) + i * 16;
        int w4 = (t & 15) * 4;
        const float* src = x + (((size_t)(b * 512 + c0 + cl)) * 64 + h) * 64 + w4;
        float4 v = *(const float4*)src;
        float p = ph[(c0 + cl) * 64 + h];
        tile[cl][w4 + 0] = v.x + p + pw[(c0 + cl) * 64 + w4 + 0];
        tile[cl][w4 + 1] = v.y + p + pw[(c0 + cl) * 64 + w4 + 1];
        tile[cl][w4 + 2] = v.z + p + pw[(c0 + cl) * 64 + w4 + 2];
        tile[cl][w4 + 3] = v.w + p + pw[(c0 + cl) * 64 + w4 + 3];
    }
    __syncthreads();
    const int wl = t >> 2, cb = (t & 3) * 16;
    bf16x8 o0, o1;
#pragma unroll
    for (int j = 0; j < 8; ++j) o0[j] = (short)f2b(tile[cb + j][wl]);
#pragma unroll
    for (int j = 0; j < 8; ++j) o1[j] = (short)f2b(tile[cb + 8 + j][wl]);
    u16* dst = y + (((size_t)(b * 64 + h) * 64 + wl) * 512 + c0 + cb);
    *(bf16x8*)dst = o0;
    *(bf16x8*)(dst + 8) = o1;
}

// ---------------------------------------------------------------------------
// weight transpose: W[k][n] f32 -> WT[n][k] bf16, all 24 matrices.
// wT per (l,axis): [ qT 512x512 | kvT 1024x512 | woT 512x512 ], ld=512
// ---------------------------------------------------------------------------
__global__ __launch_bounds__(256) void wtrans_kernel(
    const float* __restrict__ wq, const float* __restrict__ wkv,
    const float* __restrict__ wo, u16* __restrict__ wT)
{
    const int mid = blockIdx.z;
    const int l = mid / 6, rest = mid % 6, axis = rest / 3, which = rest % 3;
    const size_t la = (size_t)(l * 2 + axis);
    const float* src;
    int N;
    size_t doff;
    if (which == 0)      { src = wq  + la * 512 * 512;  N = 512;  doff = la * (2048 * 512); }
    else if (which == 1) { src = wkv + la * 512 * 1024; N = 1024; doff = la * (2048 * 512) + 512 * 512; }
    else                 { src = wo  + la * 512 * 512;  N = 512;  doff = la * (2048 * 512) + 512 * 512 + 1024 * 512; }
    const int n0 = blockIdx.y * 64;
    if (n0 >= N) return;
    const int k0 = blockIdx.x * 64;
    __shared__ float tile[64][65];
    const int t = threadIdx.x;
#pragma unroll
    for (int i = 0; i < 4; ++i) {
        int kl = (t >> 4) + i * 16;
        int n4 = (t & 15) * 4;
        float4 v = *(const float4*)(src + (size_t)(k0 + kl) * N + n0 + n4);
        tile[kl][n4 + 0] = v.x; tile[kl][n4 + 1] = v.y;
        tile[kl][n4 + 2] = v.z; tile[kl][n4 + 3] = v.w;
    }
    __syncthreads();
    const int nl = t >> 2, kb = (t & 3) * 16;
    bf16x8 o0, o1;
#pragma unroll
    for (int j = 0; j < 8; ++j) o0[j] = (short)f2b(tile[kb + j][nl]);
#pragma unroll
    for (int j = 0; j < 8; ++j) o1[j] = (short)f2b(tile[kb + 8 + j][nl]);
    u16* dst = wT + doff + (size_t)(n0 + nl) * 512 + k0 + kb;
    *(bf16x8*)dst = o0;
    *(bf16x8*)(dst + 8) = o1;
}

// ---------------------------------------------------------------------------
// Fused layer-axis kernel.  Block = one sequence of 64 tokens; 8 waves = 8
// heads.  LDS: Y 64KB (chunk-XOR swizzled, reused for O) + 1KB/wave scratch
// (16 rows x 64B).  Transposes run as TWO k-half sub-passes (write half ->
// read frag -> overwrite), per-wave sequential, no divergence.
// AXIS 0: tokens along H (row stride 64); AXIS 1: along W (stride 1).
// ---------------------------------------------------------------------------
template <int AXIS>
__global__ __launch_bounds__(512, 4) void fused_layer(
    const u16* __restrict__ y,
    const u16* __restrict__ wTla,
    const float* __restrict__ bias,
    u16* __restrict__ yout)
{
    __shared__ u16 LDS[36864];              // 72 KiB -> 2 blocks/CU
    const int tid = threadIdx.x, lane = tid & 63, wid = tid >> 6;
    const int l16 = lane & 15, g = lane >> 4;
    const int bid = blockIdx.x;
    const size_t rowbase = ((size_t)(bid >> 6) << 12) +
                           (AXIS == 0 ? (size_t)(bid & 63) : ((size_t)(bid & 63) << 6));
    const int rowstr = (AXIS == 0) ? 64 : 1;

    u16* Ys = LDS;                          // 64 rows x 512 (1KB rows, swizzled)
    u16* scr = LDS + 32768 + wid * 512;     // per-wave 1KB: 16 rows x 64B

    // ---- stage Y: 8 rows per wave, one global_load_lds row each ----
#pragma unroll
    for (int i = 0; i < 8; ++i) {
        int row = wid * 8 + i;
        const u16* src = y + (rowbase + (size_t)row * rowstr) * 512 + ((lane ^ (row & 7)) << 3);
        GLD_LDS16(src, Ys + row * 512);
    }
    __syncthreads();

    const int hoff = wid * 64;
    const u16* wq_ = wTla + (size_t)hoff * 512;
    const u16* wk_ = wTla + (size_t)(512 + hoff) * 512;
    const u16* wv_ = wTla + (size_t)(1024 + hoff) * 512;
    const u16* wo_ = wTla + (size_t)(1536) * 512;

    // y/O fragment from swizzled 64x512 region: row r, K-step t, chunk g
#define YF(r, t) (*(const bf16x8*)((const char*)Ys + (r) * 1024 + \
                    ((((t) * 4 + g) ^ ((r) & 7)) << 4)))
    // 1KB scratch, 16 rows x 64B, swizzle within row by (l16&3)<<4.
    // SW64: write 8B at half-row byte bo (in [0,64)); SF64: read 16B frag.
#define SW64(bo, val) *(uint2*)((char*)scr + l16 * 64 + (((bo) ^ ((l16 & 3) << 4)))) = (val)
#define SF64() (*(const bf16x8*)((const char*)scr + l16 * 64 + ((g * 16) ^ ((l16 & 3) << 4))))

    f32x4 acc[4][4];
    bf16x8 kf[4][2], qf[4][2];

    // ---- K projection: acc[ef][jf] = D[e][j] ----
#pragma unroll
    for (int ef = 0; ef < 4; ++ef)
#pragma unroll
        for (int jf = 0; jf < 4; ++jf) acc[ef][jf] = f32x4{0.f, 0.f, 0.f, 0.f};
#pragma unroll
    for (int t = 0; t < 16; ++t) {
        bf16x8 yf[4], wf[4];
#pragma unroll
        for (int f = 0; f < 4; ++f) {
            int row = f * 16 + l16;
            yf[f] = YF(row, t);
            wf[f] = *(const bf16x8*)(wk_ + (size_t)row * 512 + t * 32 + g * 8);
        }
#pragma unroll
        for (int ef = 0; ef < 4; ++ef)
#pragma unroll
            for (int jf = 0; jf < 4; ++jf)
                acc[ef][jf] = MFMA16(wf[ef], yf[jf], acc[ef][jf]);
    }
    // transpose: K operand rows j (=l16 per pass), k-contig e; 2 sub-passes
#pragma unroll
    for (int jf = 0; jf < 4; ++jf) {
        SW64(g * 8, pack4(acc[0][jf]));
        SW64(32 + g * 8, pack4(acc[1][jf]));
        SBAR();
        kf[jf][0] = SF64();
        SBAR();
        SW64(g * 8, pack4(acc[2][jf]));
        SW64(32 + g * 8, pack4(acc[3][jf]));
        SBAR();
        kf[jf][1] = SF64();
        SBAR();
    }

    // ---- Q projection (same structure) ----
#pragma unroll
    for (int ef = 0; ef < 4; ++ef)
#pragma unroll
        for (int jf = 0; jf < 4; ++jf) acc[ef][jf] = f32x4{0.f, 0.f, 0.f, 0.f};
#pragma unroll
    for (int t = 0; t < 16; ++t) {
        bf16x8 yf[4], wf[4];
#pragma unroll
        for (int f = 0; f < 4; ++f) {
            int row = f * 16 + l16;
            yf[f] = YF(row, t);
            wf[f] = *(const bf16x8*)(wq_ + (size_t)row * 512 + t * 32 + g * 8);
        }
#pragma unroll
        for (int ef = 0; ef < 4; ++ef)
#pragma unroll
            for (int jf = 0; jf < 4; ++jf)
                acc[ef][jf] = MFMA16(wf[ef], yf[jf], acc[ef][jf]);
    }
#pragma unroll
    for (int jf = 0; jf < 4; ++jf) {
        SW64(g * 8, pack4(acc[0][jf]));
        SW64(32 + g * 8, pack4(acc[1][jf]));
        SBAR();
        qf[jf][0] = SF64();
        SBAR();
        SW64(g * 8, pack4(acc[2][jf]));
        SW64(32 + g * 8, pack4(acc[3][jf]));
        SBAR();
        qf[jf][1] = SF64();
        SBAR();
    }

    // ---- S^T = mfma(K, Q): rows j = jf*16+g*4+r, cols i = if*16+l16 ----
    f32x4 st[4][4] = {};
#pragma unroll
    for (int k2 = 0; k2 < 2; ++k2)
#pragma unroll
        for (int i_f = 0; i_f < 4; ++i_f)
#pragma unroll
            for (int j_f = 0; j_f < 4; ++j_f)
                st[i_f][j_f] = MFMA16(kf[j_f][k2], qf[i_f][k2], st[i_f][j_f]);

    // ---- softmax over j per i; P -> pf via 2 sub-passes per i_f ----
    bf16x8 pf[4][2];
#pragma unroll
    for (int i_f = 0; i_f < 4; ++i_f) {
        float ev[4][4];
        float mx = -1e30f;
#pragma unroll
        for (int j_f = 0; j_f < 4; ++j_f)
#pragma unroll
            for (int r = 0; r < 4; ++r) {
                float v = st[i_f][j_f][r] * 0.125f;
                ev[j_f][r] = v;
                mx = fmaxf(mx, v);
            }
        mx = fmaxf(mx, __shfl_xor(mx, 16, 64));
        mx = fmaxf(mx, __shfl_xor(mx, 32, 64));
        float sum = 0.f;
#pragma unroll
        for (int j_f = 0; j_f < 4; ++j_f)
#pragma unroll
            for (int r = 0; r < 4; ++r) {
                float e = __expf(ev[j_f][r] - mx);
                ev[j_f][r] = e;
                sum += e;
            }
        sum += __shfl_xor(sum, 16, 64);
        sum += __shfl_xor(sum, 32, 64);
        float inv = __builtin_amdgcn_rcpf(sum);
        uint2 pk0, pk1, pk2, pk3;
        pk0.x = (u32)f2b(ev[0][0] * inv) | ((u32)f2b(ev[0][1] * inv) << 16);
        pk0.y = (u32)f2b(ev[0][2] * inv) | ((u32)f2b(ev[0][3] * inv) << 16);
        pk1.x = (u32)f2b(ev[1][0] * inv) | ((u32)f2b(ev[1][1] * inv) << 16);
        pk1.y = (u32)f2b(ev[1][2] * inv) | ((u32)f2b(ev[1][3] * inv) << 16);
        pk2.x = (u32)f2b(ev[2][0] * inv) | ((u32)f2b(ev[2][1] * inv) << 16);
        pk2.y = (u32)f2b(ev[2][2] * inv) | ((u32)f2b(ev[2][3] * inv) << 16);
        pk3.x = (u32)f2b(ev[3][0] * inv) | ((u32)f2b(ev[3][1] * inv) << 16);
        pk3.y = (u32)f2b(ev[3][2] * inv) | ((u32)f2b(ev[3][3] * inv) << 16);
        SW64(g * 8, pk0);
        SW64(32 + g * 8, pk1);
        SBAR();
        pf[i_f][0] = SF64();
        SBAR();
        SW64(g * 8, pk2);
        SW64(32 + g * 8, pk3);
        SBAR();
        pf[i_f][1] = SF64();
        SBAR();
    }

    // ---- V projection: acc[jf][ef] = D[j][e] ----
#pragma unroll
    for (int jf = 0; jf < 4; ++jf)
#pragma unroll
        for (int ef = 0; ef < 4; ++ef) acc[jf][ef] = f32x4{0.f, 0.f, 0.f, 0.f};
#pragma unroll
    for (int t = 0; t < 16; ++t) {
        bf16x8 yf[4], wf[4];
#pragma unroll
        for (int f = 0; f < 4; ++f) {
            int row = f * 16 + l16;
            yf[f] = YF(row, t);
            wf[f] = *(const bf16x8*)(wv_ + (size_t)row * 512 + t * 32 + g * 8);
        }
#pragma unroll
        for (int jf = 0; jf < 4; ++jf)
#pragma unroll
            for (int ef = 0; ef < 4; ++ef)
                acc[jf][ef] = MFMA16(yf[jf], wf[ef], acc[jf][ef]);
    }
    // transpose: V^T operand rows e (=l16), k-contig j; 2 sub-passes
    bf16x8 vtf[4][2];
#pragma unroll
    for (int ef = 0; ef < 4; ++ef) {
        SW64(g * 8, pack4(acc[0][ef]));
        SW64(32 + g * 8, pack4(acc[1][ef]));
        SBAR();
        vtf[ef][0] = SF64();
        SBAR();
        SW64(g * 8, pack4(acc[2][ef]));
        SW64(32 + g * 8, pack4(acc[3][ef]));
        SBAR();
        vtf[ef][1] = SF64();
        SBAR();
    }

    // ---- O^T = mfma(V^T, P): rows e = ef*16+g*4+r, cols i = if*16+l16 ----
    f32x4 of[4][4] = {};   // [ef][if]
#pragma unroll
    for (int k2 = 0; k2 < 2; ++k2)
#pragma unroll
        for (int ef = 0; ef < 4; ++ef)
#pragma unroll
            for (int i_f = 0; i_f < 4; ++i_f)
                of[ef][i_f] = MFMA16(vtf[ef][k2], pf[i_f][k2], of[ef][i_f]);

    // ---- all waves done reading Y; O overwrites the Y region ----
    __syncthreads();
#pragma unroll
    for (int ef = 0; ef < 4; ++ef)
#pragma unroll
        for (int i_f = 0; i_f < 4; ++i_f) {
            int i = i_f * 16 + l16;
            int bo = (hoff + ef * 16 + g * 4) * 2;
            *(uint2*)((char*)Ys + i * 1024 + (bo ^ ((i & 7) << 4))) = pack4(of[ef][i_f]);
        }
    __syncthreads();

    // ---- out-projection: wave covers n-cols hoff..hoff+63, K=512 ----
#pragma unroll
    for (int nf = 0; nf < 4; ++nf)
#pragma unroll
        for (int if_ = 0; if_ < 4; ++if_) acc[nf][if_] = f32x4{0.f, 0.f, 0.f, 0.f};
#pragma unroll
    for (int t = 0; t < 16; ++t) {
        bf16x8 off[4], wf[4];
#pragma unroll
        for (int f = 0; f < 4; ++f) {
            int row = f * 16 + l16;
            off[f] = YF(row, t);
            wf[f] = *(const bf16x8*)(wo_ + (size_t)(hoff + row) * 512 + t * 32 + g * 8);
        }
#pragma unroll
        for (int nf = 0; nf < 4; ++nf)
#pragma unroll
            for (int if_ = 0; if_ < 4; ++if_)
                acc[nf][if_] = MFMA16(wf[nf], off[if_], acc[nf][if_]);
    }

    // epilogue: n = hoff+nf*16+g*4 (+4 consecutive), i = if*16+l16
    float4 b4[4];
#pragma unroll
    for (int nf = 0; nf < 4; ++nf) b4[nf] = *(const float4*)(bias + hoff + nf * 16 + g * 4);
#pragma unroll
    for (int if_ = 0; if_ < 4; ++if_) {
        const int i = if_ * 16 + l16;
        u16* dst = yout + (rowbase + (size_t)i * rowstr) * 512;
#pragma unroll
        for (int nf = 0; nf < 4; ++nf) {
            const int n = hoff + nf * 16 + g * 4;
            float v0 = acc[nf][if_][0] + b4[nf].x;
            float v1 = acc[nf][if_][1] + b4[nf].y;
            float v2 = acc[nf][if_][2] + b4[nf].z;
            float v3 = acc[nf][if_][3] + b4[nf].w;
            if (AXIS == 1) {
                ushort4 o = *(const ushort4*)(dst + n);
                v0 += b2f(o.x); v1 += b2f(o.y); v2 += b2f(o.z); v3 += b2f(o.w);
            }
            uint2 pk;
            pk.x = (u32)f2b(v0) | ((u32)f2b(v1) << 16);
            pk.y = (u32)f2b(v2) | ((u32)f2b(v3) << 16);
            *(uint2*)(dst + n) = pk;
        }
    }
#undef YF
#undef SW64
#undef SF64
}

// ---------------------------------------------------------------------------
// final: y (B,H,W,C) bf16 -> out (B,C,H,W) f32
// ---------------------------------------------------------------------------
__global__ __launch_bounds__(256) void untrans_kernel(
    const u16* __restrict__ y, float* __restrict__ out)
{
    __shared__ float tile[64][65];   // [w][c]
    const int c0 = blockIdx.x * 64, h = blockIdx.y, b = blockIdx.z;
    const int t = threadIdx.x;
    {
        const int wl = t >> 2, cb = (t & 3) * 16;
        const u16* src = y + (((size_t)(b * 64 + h) * 64 + wl) * 512 + c0 + cb);
        bf16x8 v0 = *(const bf16x8*)src;
        bf16x8 v1 = *(const bf16x8*)(src + 8);
#pragma unroll
        for (int j = 0; j < 8; ++j) tile[wl][cb + j] = b2f((u16)v0[j]);
#pragma unroll
        for (int j = 0; j < 8; ++j) tile[wl][cb + 8 + j] = b2f((u16)v1[j]);
    }
    __syncthreads();
    const int cl = t >> 2, w16 = (t & 3) * 16;
    float* dst = out + (((size_t)(b * 512 + c0 + cl)) * 64 + h) * 64 + w16;
#pragma unroll
    for (int j = 0; j < 4; ++j) {
        float4 v;
        v.x = tile[w16 + j * 4 + 0][cl];
        v.y = tile[w16 + j * 4 + 1][cl];
        v.z = tile[w16 + j * 4 + 2][cl];
        v.w = tile[w16 + j * 4 + 3][cl];
        *(float4*)(dst + j * 4) = v;
    }
}

// ---------------------------------------------------------------------------
extern "C" void kernel_launch(void* const* d_in, const int* in_sizes, int n_in,
                              void* d_out, int out_size, void* d_ws, size_t ws_size,
                              hipStream_t stream)
{
    (void)in_sizes; (void)n_in; (void)out_size; (void)ws_size;
    const float* x   = (const float*)d_in[0];
    const float* ph  = (const float*)d_in[1];
    const float* pw  = (const float*)d_in[2];
    const float* wq  = (const float*)d_in[3];
    const float* wkv = (const float*)d_in[4];
    const float* wo  = (const float*)d_in[5];
    const float* wob = (const float*)d_in[6];

    char* ws = (char*)d_ws;
    u16* yA = (u16*)(ws);                   // 32 MB
    u16* yB = (u16*)(ws + 33554432);        // 32 MB
    u16* wT = (u16*)(ws + 67108864);        // 16 MB: transposed weights bf16
    float* out = (float*)d_out;

    embed_kernel<<<dim3(8, 64, 8), 256, 0, stream>>>(x, ph, pw, yA);
    wtrans_kernel<<<dim3(8, 16, 24), 256, 0, stream>>>(wq, wkv, wo, wT);

    u16* yin = yA;
    u16* yout = yB;
    for (int l = 0; l < 4; ++l) {
        for (int axis = 0; axis < 2; ++axis) {
            const u16* wTla = wT + (size_t)(l * 2 + axis) * 2048 * 512;
            const float* bias = wob + (size_t)(l * 2 + axis) * 512;
            if (axis == 0)
                fused_layer<0><<<dim3(512), 512, 0, stream>>>(yin, wTla, bias, yout);
            else
                fused_layer<1><<<dim3(512), 512, 0, stream>>>(yin, wTla, bias, yout);
        }
        u16* tmp = yin; yin = yout; yout = tmp;
    }
    untrans_kernel<<<dim3(8, 64, 8), 256, 0, stream>>>(yin, out);
}

// Round 9
// 1162.496 us; speedup vs baseline: 1.5791x; 1.1674x over previous
//
#include <hip/hip_runtime.h>
#include <stdint.h>

// ---------------------------------------------------------------------------
// SpatialAggregator: axial attention, B=8 C=512 H=W=64, DEPTH=4, HEADS=8
// R9: R8 structure (72KB LDS, 1KB/wave scratch, 2-subpass transposes) with
// __launch_bounds__(512,2): VGPR cap 128 (no spill) while LDS permits
// 2 blocks/CU -> 4 waves/SIMD.  (R8's (512,4) capped VGPR at 64 -> spill.)
// ---------------------------------------------------------------------------

typedef __attribute__((ext_vector_type(8))) short bf16x8;
typedef __attribute__((ext_vector_type(4))) float f32x4;
typedef unsigned short u16;
typedef unsigned int u32;

#define MFMA16(a, b, c) __builtin_amdgcn_mfma_f32_16x16x32_bf16((a), (b), (c), 0, 0, 0)
#define SBAR() __builtin_amdgcn_sched_barrier(0)

__device__ __forceinline__ float b2f(u16 h) {
    u32 u = ((u32)h) << 16;
    float f;
    __builtin_memcpy(&f, &u, 4);
    return f;
}
__device__ __forceinline__ u16 f2b(float f) {
    u32 u;
    __builtin_memcpy(&u, &f, 4);
    u32 r = (u + 0x7fffu + ((u >> 16) & 1u)) >> 16;   // RNE
    return (u16)r;
}
__device__ __forceinline__ uint2 pack4(const f32x4& v) {
    uint2 pk;
    pk.x = (u32)f2b(v[0]) | ((u32)f2b(v[1]) << 16);
    pk.y = (u32)f2b(v[2]) | ((u32)f2b(v[3]) << 16);
    return pk;
}

#define GLD_LDS16(g, l)                                                        \
    __builtin_amdgcn_global_load_lds(                                          \
        (const __attribute__((address_space(1))) void*)(g),                    \
        (__attribute__((address_space(3))) void*)(l), 16, 0, 0)

// ---------------------------------------------------------------------------
// embed: x (B,C,H,W) f32 + pos_h (C,H) + pos_w (C,W) -> y (B,H,W,C) bf16
// ---------------------------------------------------------------------------
__global__ __launch_bounds__(256) void embed_kernel(
    const float* __restrict__ x, const float* __restrict__ ph,
    const float* __restrict__ pw, u16* __restrict__ y)
{
    __shared__ float tile[64][65];
    const int c0 = blockIdx.x * 64, h = blockIdx.y, b = blockIdx.z;
    const int t = threadIdx.x;
#pragma unroll
    for (int i = 0; i < 4; ++i) {
        int cl = (t >> 4) + i * 16;
        int w4 = (t & 15) * 4;
        const float* src = x + (((size_t)(b * 512 + c0 + cl)) * 64 + h) * 64 + w4;
        float4 v = *(const float4*)src;
        float p = ph[(c0 + cl) * 64 + h];
        tile[cl][w4 + 0] = v.x + p + pw[(c0 + cl) * 64 + w4 + 0];
        tile[cl][w4 + 1] = v.y + p + pw[(c0 + cl) * 64 + w4 + 1];
        tile[cl][w4 + 2] = v.z + p + pw[(c0 + cl) * 64 + w4 + 2];
        tile[cl][w4 + 3] = v.w + p + pw[(c0 + cl) * 64 + w4 + 3];
    }
    __syncthreads();
    const int wl = t >> 2, cb = (t & 3) * 16;
    bf16x8 o0, o1;
#pragma unroll
    for (int j = 0; j < 8; ++j) o0[j] = (short)f2b(tile[cb + j][wl]);
#pragma unroll
    for (int j = 0; j < 8; ++j) o1[j] = (short)f2b(tile[cb + 8 + j][wl]);
    u16* dst = y + (((size_t)(b * 64 + h) * 64 + wl) * 512 + c0 + cb);
    *(bf16x8*)dst = o0;
    *(bf16x8*)(dst + 8) = o1;
}

// ---------------------------------------------------------------------------
// weight transpose: W[k][n] f32 -> WT[n][k] bf16, all 24 matrices.
// wT per (l,axis): [ qT 512x512 | kvT 1024x512 | woT 512x512 ], ld=512
// ---------------------------------------------------------------------------
__global__ __launch_bounds__(256) void wtrans_kernel(
    const float* __restrict__ wq, const float* __restrict__ wkv,
    const float* __restrict__ wo, u16* __restrict__ wT)
{
    const int mid = blockIdx.z;
    const int l = mid / 6, rest = mid % 6, axis = rest / 3, which = rest % 3;
    const size_t la = (size_t)(l * 2 + axis);
    const float* src;
    int N;
    size_t doff;
    if (which == 0)      { src = wq  + la * 512 * 512;  N = 512;  doff = la * (2048 * 512); }
    else if (which == 1) { src = wkv + la * 512 * 1024; N = 1024; doff = la * (2048 * 512) + 512 * 512; }
    else                 { src = wo  + la * 512 * 512;  N = 512;  doff = la * (2048 * 512) + 512 * 512 + 1024 * 512; }
    const int n0 = blockIdx.y * 64;
    if (n0 >= N) return;
    const int k0 = blockIdx.x * 64;
    __shared__ float tile[64][65];
    const int t = threadIdx.x;
#pragma unroll
    for (int i = 0; i < 4; ++i) {
        int kl = (t >> 4) + i * 16;
        int n4 = (t & 15) * 4;
        float4 v = *(const float4*)(src + (size_t)(k0 + kl) * N + n0 + n4);
        tile[kl][n4 + 0] = v.x; tile[kl][n4 + 1] = v.y;
        tile[kl][n4 + 2] = v.z; tile[kl][n4 + 3] = v.w;
    }
    __syncthreads();
    const int nl = t >> 2, kb = (t & 3) * 16;
    bf16x8 o0, o1;
#pragma unroll
    for (int j = 0; j < 8; ++j) o0[j] = (short)f2b(tile[kb + j][nl]);
#pragma unroll
    for (int j = 0; j < 8; ++j) o1[j] = (short)f2b(tile[kb + 8 + j][nl]);
    u16* dst = wT + doff + (size_t)(n0 + nl) * 512 + k0 + kb;
    *(bf16x8*)dst = o0;
    *(bf16x8*)(dst + 8) = o1;
}

// ---------------------------------------------------------------------------
// Fused layer-axis kernel.  Block = one sequence of 64 tokens; 8 waves = 8
// heads.  LDS: Y 64KB (chunk-XOR swizzled, reused for O) + 1KB/wave scratch
// (16 rows x 64B).  Transposes run as TWO k-half sub-passes (write half ->
// read frag -> overwrite), per-wave sequential, no divergence.
// AXIS 0: tokens along H (row stride 64); AXIS 1: along W (stride 1).
// ---------------------------------------------------------------------------
template <int AXIS>
__global__ __launch_bounds__(512, 2) void fused_layer(
    const u16* __restrict__ y,
    const u16* __restrict__ wTla,
    const float* __restrict__ bias,
    u16* __restrict__ yout)
{
    __shared__ u16 LDS[36864];              // 72 KiB -> 2 blocks/CU
    const int tid = threadIdx.x, lane = tid & 63, wid = tid >> 6;
    const int l16 = lane & 15, g = lane >> 4;
    const int bid = blockIdx.x;
    const size_t rowbase = ((size_t)(bid >> 6) << 12) +
                           (AXIS == 0 ? (size_t)(bid & 63) : ((size_t)(bid & 63) << 6));
    const int rowstr = (AXIS == 0) ? 64 : 1;

    u16* Ys = LDS;                          // 64 rows x 512 (1KB rows, swizzled)
    u16* scr = LDS + 32768 + wid * 512;     // per-wave 1KB: 16 rows x 64B

    // ---- stage Y: 8 rows per wave, one global_load_lds row each ----
#pragma unroll
    for (int i = 0; i < 8; ++i) {
        int row = wid * 8 + i;
        const u16* src = y + (rowbase + (size_t)row * rowstr) * 512 + ((lane ^ (row & 7)) << 3);
        GLD_LDS16(src, Ys + row * 512);
    }
    __syncthreads();

    const int hoff = wid * 64;
    const u16* wq_ = wTla + (size_t)hoff * 512;
    const u16* wk_ = wTla + (size_t)(512 + hoff) * 512;
    const u16* wv_ = wTla + (size_t)(1024 + hoff) * 512;
    const u16* wo_ = wTla + (size_t)(1536) * 512;

    // y/O fragment from swizzled 64x512 region: row r, K-step t, chunk g
#define YF(r, t) (*(const bf16x8*)((const char*)Ys + (r) * 1024 + \
                    ((((t) * 4 + g) ^ ((r) & 7)) << 4)))
    // 1KB scratch, 16 rows x 64B, swizzle within row by (l16&3)<<4.
    // SW64: write 8B at half-row byte bo (in [0,64)); SF64: read 16B frag.
#define SW64(bo, val) *(uint2*)((char*)scr + l16 * 64 + (((bo) ^ ((l16 & 3) << 4)))) = (val)
#define SF64() (*(const bf16x8*)((const char*)scr + l16 * 64 + ((g * 16) ^ ((l16 & 3) << 4))))

    f32x4 acc[4][4];
    bf16x8 kf[4][2], qf[4][2];

    // ---- K projection: acc[ef][jf] = D[e][j] ----
#pragma unroll
    for (int ef = 0; ef < 4; ++ef)
#pragma unroll
        for (int jf = 0; jf < 4; ++jf) acc[ef][jf] = f32x4{0.f, 0.f, 0.f, 0.f};
#pragma unroll
    for (int t = 0; t < 16; ++t) {
        bf16x8 yf[4], wf[4];
#pragma unroll
        for (int f = 0; f < 4; ++f) {
            int row = f * 16 + l16;
            yf[f] = YF(row, t);
            wf[f] = *(const bf16x8*)(wk_ + (size_t)row * 512 + t * 32 + g * 8);
        }
#pragma unroll
        for (int ef = 0; ef < 4; ++ef)
#pragma unroll
            for (int jf = 0; jf < 4; ++jf)
                acc[ef][jf] = MFMA16(wf[ef], yf[jf], acc[ef][jf]);
    }
    // transpose: K operand rows j (=l16 per pass), k-contig e; 2 sub-passes
#pragma unroll
    for (int jf = 0; jf < 4; ++jf) {
        SW64(g * 8, pack4(acc[0][jf]));
        SW64(32 + g * 8, pack4(acc[1][jf]));
        SBAR();
        kf[jf][0] = SF64();
        SBAR();
        SW64(g * 8, pack4(acc[2][jf]));
        SW64(32 + g * 8, pack4(acc[3][jf]));
        SBAR();
        kf[jf][1] = SF64();
        SBAR();
    }

    // ---- Q projection (same structure) ----
#pragma unroll
    for (int ef = 0; ef < 4; ++ef)
#pragma unroll
        for (int jf = 0; jf < 4; ++jf) acc[ef][jf] = f32x4{0.f, 0.f, 0.f, 0.f};
#pragma unroll
    for (int t = 0; t < 16; ++t) {
        bf16x8 yf[4], wf[4];
#pragma unroll
        for (int f = 0; f < 4; ++f) {
            int row = f * 16 + l16;
            yf[f] = YF(row, t);
            wf[f] = *(const bf16x8*)(wq_ + (size_t)row * 512 + t * 32 + g * 8);
        }
#pragma unroll
        for (int ef = 0; ef < 4; ++ef)
#pragma unroll
            for (int jf = 0; jf < 4; ++jf)
                acc[ef][jf] = MFMA16(wf[ef], yf[jf], acc[ef][jf]);
    }
#pragma unroll
    for (int jf = 0; jf < 4; ++jf) {
        SW64(g * 8, pack4(acc[0][jf]));
        SW64(32 + g * 8, pack4(acc[1][jf]));
        SBAR();
        qf[jf][0] = SF64();
        SBAR();
        SW64(g * 8, pack4(acc[2][jf]));
        SW64(32 + g * 8, pack4(acc[3][jf]));
        SBAR();
        qf[jf][1] = SF64();
        SBAR();
    }

    // ---- S^T = mfma(K, Q): rows j = jf*16+g*4+r, cols i = if*16+l16 ----
    f32x4 st[4][4] = {};
#pragma unroll
    for (int k2 = 0; k2 < 2; ++k2)
#pragma unroll
        for (int i_f = 0; i_f < 4; ++i_f)
#pragma unroll
            for (int j_f = 0; j_f < 4; ++j_f)
                st[i_f][j_f] = MFMA16(kf[j_f][k2], qf[i_f][k2], st[i_f][j_f]);

    // ---- softmax over j per i; P -> pf via 2 sub-passes per i_f ----
    bf16x8 pf[4][2];
#pragma unroll
    for (int i_f = 0; i_f < 4; ++i_f) {
        float ev[4][4];
        float mx = -1e30f;
#pragma unroll
        for (int j_f = 0; j_f < 4; ++j_f)
#pragma unroll
            for (int r = 0; r < 4; ++r) {
                float v = st[i_f][j_f][r] * 0.125f;
                ev[j_f][r] = v;
                mx = fmaxf(mx, v);
            }
        mx = fmaxf(mx, __shfl_xor(mx, 16, 64));
        mx = fmaxf(mx, __shfl_xor(mx, 32, 64));
        float sum = 0.f;
#pragma unroll
        for (int j_f = 0; j_f < 4; ++j_f)
#pragma unroll
            for (int r = 0; r < 4; ++r) {
                float e = __expf(ev[j_f][r] - mx);
                ev[j_f][r] = e;
                sum += e;
            }
        sum += __shfl_xor(sum, 16, 64);
        sum += __shfl_xor(sum, 32, 64);
        float inv = __builtin_amdgcn_rcpf(sum);
        uint2 pk0, pk1, pk2, pk3;
        pk0.x = (u32)f2b(ev[0][0] * inv) | ((u32)f2b(ev[0][1] * inv) << 16);
        pk0.y = (u32)f2b(ev[0][2] * inv) | ((u32)f2b(ev[0][3] * inv) << 16);
        pk1.x = (u32)f2b(ev[1][0] * inv) | ((u32)f2b(ev[1][1] * inv) << 16);
        pk1.y = (u32)f2b(ev[1][2] * inv) | ((u32)f2b(ev[1][3] * inv) << 16);
        pk2.x = (u32)f2b(ev[2][0] * inv) | ((u32)f2b(ev[2][1] * inv) << 16);
        pk2.y = (u32)f2b(ev[2][2] * inv) | ((u32)f2b(ev[2][3] * inv) << 16);
        pk3.x = (u32)f2b(ev[3][0] * inv) | ((u32)f2b(ev[3][1] * inv) << 16);
        pk3.y = (u32)f2b(ev[3][2] * inv) | ((u32)f2b(ev[3][3] * inv) << 16);
        SW64(g * 8, pk0);
        SW64(32 + g * 8, pk1);
        SBAR();
        pf[i_f][0] = SF64();
        SBAR();
        SW64(g * 8, pk2);
        SW64(32 + g * 8, pk3);
        SBAR();
        pf[i_f][1] = SF64();
        SBAR();
    }

    // ---- V projection: acc[jf][ef] = D[j][e] ----
#pragma unroll
    for (int jf = 0; jf < 4; ++jf)
#pragma unroll
        for (int ef = 0; ef < 4; ++ef) acc[jf][ef] = f32x4{0.f, 0.f, 0.f, 0.f};
#pragma unroll
    for (int t = 0; t < 16; ++t) {
        bf16x8 yf[4], wf[4];
#pragma unroll
        for (int f = 0; f < 4; ++f) {
            int row = f * 16 + l16;
            yf[f] = YF(row, t);
            wf[f] = *(const bf16x8*)(wv_ + (size_t)row * 512 + t * 32 + g * 8);
        }
#pragma unroll
        for (int jf = 0; jf < 4; ++jf)
#pragma unroll
            for (int ef = 0; ef < 4; ++ef)
                acc[jf][ef] = MFMA16(yf[jf], wf[ef], acc[jf][ef]);
    }
    // transpose: V^T operand rows e (=l16), k-contig j; 2 sub-passes
    bf16x8 vtf[4][2];
#pragma unroll
    for (int ef = 0; ef < 4; ++ef) {
        SW64(g * 8, pack4(acc[0][ef]));
        SW64(32 + g * 8, pack4(acc[1][ef]));
        SBAR();
        vtf[ef][0] = SF64();
        SBAR();
        SW64(g * 8, pack4(acc[2][ef]));
        SW64(32 + g * 8, pack4(acc[3][ef]));
        SBAR();
        vtf[ef][1] = SF64();
        SBAR();
    }

    // ---- O^T = mfma(V^T, P): rows e = ef*16+g*4+r, cols i = if*16+l16 ----
    f32x4 of[4][4] = {};   // [ef][if]
#pragma unroll
    for (int k2 = 0; k2 < 2; ++k2)
#pragma unroll
        for (int ef = 0; ef < 4; ++ef)
#pragma unroll
            for (int i_f = 0; i_f < 4; ++i_f)
                of[ef][i_f] = MFMA16(vtf[ef][k2], pf[i_f][k2], of[ef][i_f]);

    // ---- all waves done reading Y; O overwrites the Y region ----
    __syncthreads();
#pragma unroll
    for (int ef = 0; ef < 4; ++ef)
#pragma unroll
        for (int i_f = 0; i_f < 4; ++i_f) {
            int i = i_f * 16 + l16;
            int bo = (hoff + ef * 16 + g * 4) * 2;
            *(uint2*)((char*)Ys + i * 1024 + (bo ^ ((i & 7) << 4))) = pack4(of[ef][i_f]);
        }
    __syncthreads();

    // ---- out-projection: wave covers n-cols hoff..hoff+63, K=512 ----
#pragma unroll
    for (int nf = 0; nf < 4; ++nf)
#pragma unroll
        for (int if_ = 0; if_ < 4; ++if_) acc[nf][if_] = f32x4{0.f, 0.f, 0.f, 0.f};
#pragma unroll
    for (int t = 0; t < 16; ++t) {
        bf16x8 off[4], wf[4];
#pragma unroll
        for (int f = 0; f < 4; ++f) {
            int row = f * 16 + l16;
            off[f] = YF(row, t);
            wf[f] = *(const bf16x8*)(wo_ + (size_t)(hoff + row) * 512 + t * 32 + g * 8);
        }
#pragma unroll
        for (int nf = 0; nf < 4; ++nf)
#pragma unroll
            for (int if_ = 0; if_ < 4; ++if_)
                acc[nf][if_] = MFMA16(wf[nf], off[if_], acc[nf][if_]);
    }

    // epilogue: n = hoff+nf*16+g*4 (+4 consecutive), i = if*16+l16
    float4 b4[4];
#pragma unroll
    for (int nf = 0; nf < 4; ++nf) b4[nf] = *(const float4*)(bias + hoff + nf * 16 + g * 4);
#pragma unroll
    for (int if_ = 0; if_ < 4; ++if_) {
        const int i = if_ * 16 + l16;
        u16* dst = yout + (rowbase + (size_t)i * rowstr) * 512;
#pragma unroll
        for (int nf = 0; nf < 4; ++nf) {
            const int n = hoff + nf * 16 + g * 4;
            float v0 = acc[nf][if_][0] + b4[nf].x;
            float v1 = acc[nf][if_][1] + b4[nf].y;
            float v2 = acc[nf][if_][2] + b4[nf].z;
            float v3 = acc[nf][if_][3] + b4[nf].w;
            if (AXIS == 1) {
                ushort4 o = *(const ushort4*)(dst + n);
                v0 += b2f(o.x); v1 += b2f(o.y); v2 += b2f(o.z); v3 += b2f(o.w);
            }
            uint2 pk;
            pk.x = (u32)f2b(v0) | ((u32)f2b(v1) << 16);
            pk.y = (u32)f2b(v2) | ((u32)f2b(v3) << 16);
            *(uint2*)(dst + n) = pk;
        }
    }
#undef YF
#undef SW64
#undef SF64
}

// ---------------------------------------------------------------------------
// final: y (B,H,W,C) bf16 -> out (B,C,H,W) f32
// ---------------------------------------------------------------------------
__global__ __launch_bounds__(256) void untrans_kernel(
    const u16* __restrict__ y, float* __restrict__ out)
{
    __shared__ float tile[64][65];   // [w][c]
    const int c0 = blockIdx.x * 64, h = blockIdx.y, b = blockIdx.z;
    const int t = threadIdx.x;
    {
        const int wl = t >> 2, cb = (t & 3) * 16;
        const u16* src = y + (((size_t)(b * 64 + h) * 64 + wl) * 512 + c0 + cb);
        bf16x8 v0 = *(const bf16x8*)src;
        bf16x8 v1 = *(const bf16x8*)(src + 8);
#pragma unroll
        for (int j = 0; j < 8; ++j) tile[wl][cb + j] = b2f((u16)v0[j]);
#pragma unroll
        for (int j = 0; j < 8; ++j) tile[wl][cb + 8 + j] = b2f((u16)v1[j]);
    }
    __syncthreads();
    const int cl = t >> 2, w16 = (t & 3) * 16;
    float* dst = out + (((size_t)(b * 512 + c0 + cl)) * 64 + h) * 64 + w16;
#pragma unroll
    for (int j = 0; j < 4; ++j) {
        float4 v;
        v.x = tile[w16 + j * 4 + 0][cl];
        v.y = tile[w16 + j * 4 + 1][cl];
        v.z = tile[w16 + j * 4 + 2][cl];
        v.w = tile[w16 + j * 4 + 3][cl];
        *(float4*)(dst + j * 4) = v;
    }
}

// ---------------------------------------------------------------------------
extern "C" void kernel_launch(void* const* d_in, const int* in_sizes, int n_in,
                              void* d_out, int out_size, void* d_ws, size_t ws_size,
                              hipStream_t stream)
{
    (void)in_sizes; (void)n_in; (void)out_size; (void)ws_size;
    const float* x   = (const float*)d_in[0];
    const float* ph  = (const float*)d_in[1];
    const float* pw  = (const float*)d_in[2];
    const float* wq  = (const float*)d_in[3];
    const float* wkv = (const float*)d_in[4];
    const float* wo  = (const float*)d_in[5];
    const float* wob = (const float*)d_in[6];

    char* ws = (char*)d_ws;
    u16* yA = (u16*)(ws);                   // 32 MB
    u16* yB = (u16*)(ws + 33554432);        // 32 MB
    u16* wT = (u16*)(ws + 67108864);        // 16 MB: transposed weights bf16
    float* out = (float*)d_out;

    embed_kernel<<<dim3(8, 64, 8), 256, 0, stream>>>(x, ph, pw, yA);
    wtrans_kernel<<<dim3(8, 16, 24), 256, 0, stream>>>(wq, wkv, wo, wT);

    u16* yin = yA;
    u16* yout = yB;
    for (int l = 0; l < 4; ++l) {
        for (int axis = 0; axis < 2; ++axis) {
            const u16* wTla = wT + (size_t)(l * 2 + axis) * 2048 * 512;
            const float* bias = wob + (size_t)(l * 2 + axis) * 512;
            if (axis == 0)
                fused_layer<0><<<dim3(512), 512, 0, stream>>>(yin, wTla, bias, yout);
            else
                fused_layer<1><<<dim3(512), 512, 0, stream>>>(yin, wTla, bias, yout);
        }
        u16* tmp = yin; yin = yout; yout = tmp;
    }
    untrans_kernel<<<dim3(8, 64, 8), 256, 0, stream>>>(yin, out);
}